// Round 1
// baseline (761.997 us; speedup 1.0000x reference)
//
#include <hip/hip_runtime.h>

#define BB 64
#define TT 32
#define NN 15
#define FF 1536
#define DD 768

typedef __attribute__((ext_vector_type(8))) __bf16 bf16x8;
typedef __attribute__((ext_vector_type(4))) float f32x4;

__device__ __forceinline__ unsigned short f2bf(float f) {
  unsigned x = __float_as_uint(f);
  return (unsigned short)((x + 0x7fffu + ((x >> 16) & 1u)) >> 16);
}
__device__ __forceinline__ float bf2f(unsigned short u) {
  return __uint_as_float(((unsigned)u) << 16);
}

__device__ __forceinline__ void gll16(const void* g, void* l) {
  __builtin_amdgcn_global_load_lds((const __attribute__((address_space(1))) void*)g,
                                   (__attribute__((address_space(3))) void*)l, 16, 0, 0);
}

// ---------------- init min/max scalars ----------------
__global__ void k_init(unsigned* mmx) {
  if (threadIdx.x == 0) { mmx[0] = 0x7f800000u; mmx[1] = 0u; }
}

// ---------------- label diff norms + global min/max ----------------
__global__ __launch_bounds__(256) void k_nrm(const float* __restrict__ labels,
                                             float* __restrict__ nrm, unsigned* mmx) {
  int idx = blockIdx.x * 256 + threadIdx.x;  // over B*(T-1)*(N-1) = 27776
  const int total = BB * (TT - 1) * (NN - 1);
  bool valid = idx < total;
  float v = 0.f;
  if (valid) {
    int j = idx % (NN - 1);
    int bt = idx / (NN - 1);
    int tt = bt % (TT - 1);           // 0..30, diff between t=tt+1 and t=tt
    int b = bt / (TT - 1);
    const float* l0 = labels + ((size_t)(b * TT + tt) * (NN - 1) + j) * 3;
    const float* l1 = l0 + (NN - 1) * 3;
    float dx = l1[0] - l0[0], dy = l1[1] - l0[1], dz = l1[2] - l0[2];
    v = sqrtf(dx * dx + dy * dy + dz * dz);
    nrm[(b * TT + tt + 1) * (NN - 1) + j] = v;
  }
  float vmin = valid ? v : __builtin_inff();
  float vmax = valid ? v : 0.f;
  #pragma unroll
  for (int off = 32; off; off >>= 1) {
    vmin = fminf(vmin, __shfl_down(vmin, off));
    vmax = fmaxf(vmax, __shfl_down(vmax, off));
  }
  if ((threadIdx.x & 63) == 0) {
    atomicMin(&mmx[0], __float_as_uint(vmin));  // valid: all values >= 0
    atomicMax(&mmx[1], __float_as_uint(vmax));
  }
}

// ---------------- W transpose + bf16 convert: Wt[mat][n][d][f] ----------------
__global__ __launch_bounds__(256) void k_cvtw(const float* __restrict__ Wk,
                                              const float* __restrict__ Wv,
                                              unsigned short* __restrict__ Wt) {
  __shared__ float tile[64][65];
  int bid = blockIdx.x;                 // 2*15*24*12 = 8640
  int mat = bid / 4320; int rem = bid % 4320;
  int n = rem / 288; int tl = rem % 288;
  int ft = tl % 24, dt = tl / 24;
  const float* W = (mat ? Wv : Wk) + (size_t)n * FF * DD;
  int tid = threadIdx.x;
  #pragma unroll
  for (int it = 0; it < 16; it++) {
    int idx = tid + it * 256;
    int r = idx >> 6, c = idx & 63;     // r: f-local, c: d-local
    tile[r][c] = W[(size_t)(ft * 64 + r) * DD + dt * 64 + c];
  }
  __syncthreads();
  unsigned short* O = Wt + ((size_t)(mat * NN + n) * DD + dt * 64) * FF + ft * 64;
  #pragma unroll
  for (int it = 0; it < 16; it++) {
    int idx = tid + it * 256;
    int r = idx >> 6, c = idx & 63;     // r: d-local, c: f-local
    O[(size_t)r * FF + c] = f2bf(tile[c][r]);
  }
}

// ---------------- x -> bf16 convert fused with gate dot ----------------
__global__ __launch_bounds__(256) void k_cvtx(const float* __restrict__ x,
                                              const float* __restrict__ w_in,
                                              const float* __restrict__ b_in,
                                              const float* __restrict__ nrm,
                                              const unsigned* __restrict__ mmx,
                                              unsigned short* __restrict__ xb,
                                              float* __restrict__ Iw) {
  int rid = blockIdx.x * 4 + (threadIdx.x >> 6);  // row over B*T*N = 30720
  int lane = threadIdx.x & 63;
  const float* xr = x + (size_t)rid * FF;
  unsigned short* xo = xb + (size_t)rid * FF;
  float acc = 0.f;
  #pragma unroll
  for (int i = 0; i < 6; i++) {
    float4 v = *(const float4*)(xr + lane * 4 + i * 256);
    float4 w = *(const float4*)(w_in + lane * 4 + i * 256);
    acc += v.x * w.x + v.y * w.y + v.z * w.z + v.w * w.w;
    ushort4 o;
    o.x = f2bf(v.x); o.y = f2bf(v.y); o.z = f2bf(v.z); o.w = f2bf(v.w);
    *(ushort4*)(xo + lane * 4 + i * 256) = o;
  }
  #pragma unroll
  for (int off = 32; off; off >>= 1) acc += __shfl_down(acc, off);
  if (lane == 0) {
    int n = rid % NN;
    int bt = rid / NN;
    int t = bt & 31, b = bt >> 5;
    float a = acc + b_in[0];
    if (n < NN - 1 && t > 0) {
      float mn = __uint_as_float(mmx[0]), mx = __uint_as_float(mmx[1]);
      float nv = nrm[(b * TT + t) * (NN - 1) + n];
      a += 0.1f * ((nv - mn) / (mx - mn) * 2.f - 1.f);
    }
    Iw[rid] = 1.f / (1.f + expf(-a));
  }
}

// ---------------- gate suffix products ----------------
__global__ void k_suffix(const float* __restrict__ Iw, float* __restrict__ Cw,
                         float* __restrict__ Callw) {
  int id = blockIdx.x * 256 + threadIdx.x;
  if (id < BB * NN) {
    int b = id / NN, n = id % NN;
    float suf = 1.f;
    for (int t = TT - 1; t >= 0; t--) {
      float I = Iw[(b * TT + t) * NN + n];
      Cw[(b * TT + t) * NN + n] = I * suf;
      suf *= (1.f - I);
    }
    Callw[id] = suf;
  }
}

// ---------------- out init: cell_past * prod(F) ----------------
__global__ void k_outinit(const float* __restrict__ cell_past,
                          const float* __restrict__ Callw, float* __restrict__ out) {
  int idx = blockIdx.x * 256 + threadIdx.x;
  if (idx < BB * NN * NN) out[idx] = cell_past[idx] * Callw[idx / NN];
}

// ---------------- main GEMM: kv_raw[mat][t][b][n][d] (bf16, pre-bias, pre-LN) ----------------
__global__ __launch_bounds__(256) void k_gemm(const unsigned short* __restrict__ xb,
                                              const unsigned short* __restrict__ Wt,
                                              unsigned short* __restrict__ kvb) {
  __shared__ unsigned short As[128 * 64];
  __shared__ unsigned short Bs[128 * 64];
  int bid = blockIdx.x;                       // 2880 = 8 * 360, bijective XCD swizzle
  int swz = (bid & 7) * 360 + (bid >> 3);
  int matn = swz / 96, tile = swz % 96;
  int mt = tile & 15, ntt = tile >> 4;        // 16 m-tiles fastest (share Wt panel)
  int mat = matn / 15, n = matn % 15;
  const unsigned short* Ag = xb + (size_t)mt * 128 * (NN * FF) + n * FF;
  const unsigned short* Bg = Wt + ((size_t)(mat * NN + n) * DD + ntt * 128) * FF;
  int tid = threadIdx.x;
  int wave = tid >> 6, lane = tid & 63;
  int sr = tid >> 3;                          // 0..31 rows per issue
  int skb = (tid & 7) * 16;                   // byte within 128B LDS row
  int hi = lane >> 4, lo = lane & 15;
  int wm = wave >> 1, wn = wave & 1;

  f32x4 acc[4][4];
  #pragma unroll
  for (int i = 0; i < 4; i++)
    #pragma unroll
    for (int j = 0; j < 4; j++) acc[i][j] = (f32x4)0.f;

  for (int kt = 0; kt < FF; kt += 64) {
    __syncthreads();
    #pragma unroll
    for (int j = 0; j < 4; j++) {
      int r = j * 32 + sr;
      int ks = (skb ^ ((r & 7) << 4)) >> 1;   // pre-swizzled global source (elem units)
      gll16(Ag + (size_t)r * (NN * FF) + kt + ks, (char*)As + j * 4096 + wave * 1024);
      gll16(Bg + (size_t)r * FF + kt + ks, (char*)Bs + j * 4096 + wave * 1024);
    }
    asm volatile("s_waitcnt vmcnt(0)" ::: "memory");
    __syncthreads();
    #pragma unroll
    for (int ks = 0; ks < 2; ks++) {
      bf16x8 af[4], bfr[4];
      #pragma unroll
      for (int i = 0; i < 4; i++) {
        int row = wm * 64 + i * 16 + lo;
        int kb = ks * 64 + hi * 16;
        af[i] = *(const bf16x8*)((const char*)As + row * 128 + (kb ^ ((row & 7) << 4)));
        int drow = wn * 64 + i * 16 + lo;
        bfr[i] = *(const bf16x8*)((const char*)Bs + drow * 128 + (kb ^ ((drow & 7) << 4)));
      }
      #pragma unroll
      for (int i = 0; i < 4; i++)
        #pragma unroll
        for (int j = 0; j < 4; j++)
          acc[i][j] = __builtin_amdgcn_mfma_f32_16x16x32_bf16(af[i], bfr[j], acc[i][j], 0, 0, 0);
    }
  }
  unsigned short* outp = kvb + (size_t)mat * (TT * BB * NN * DD);
  #pragma unroll
  for (int i = 0; i < 4; i++) {
    int rbase = mt * 128 + wm * 64 + i * 16 + hi * 4;
    #pragma unroll
    for (int j = 0; j < 4; j++) {
      int d = ntt * 128 + wn * 64 + j * 16 + lo;
      #pragma unroll
      for (int q = 0; q < 4; q++) {
        int rg = rbase + q;
        int b = rg >> 5, t = rg & 31;
        outp[((size_t)(t * BB + b) * NN + n) * DD + d] = f2bf(acc[i][j][q]);
      }
    }
  }
}

// ---------------- scan: bias+LN+softplus, 15x15 MFMA dots, LN over m, gated sum ----------------
__global__ __launch_bounds__(256) void k_scan(const unsigned short* __restrict__ kvb,
                                              const float* __restrict__ bk,
                                              const float* __restrict__ bv,
                                              const float* __restrict__ kg,
                                              const float* __restrict__ kbe,
                                              const float* __restrict__ vg,
                                              const float* __restrict__ vbe,
                                              const float* __restrict__ ng,
                                              const float* __restrict__ nbe,
                                              const float* __restrict__ Cw,
                                              float* __restrict__ out) {
  __shared__ unsigned short Kl[16 * 776];
  __shared__ unsigned short Vl[16 * 776];
  __shared__ float Sl[4][16][16];
  __shared__ float Ss[16][16];
  int bt = blockIdx.x;                    // t*64 + b
  int t = bt >> 6, b = bt & 63;
  int tid = threadIdx.x, wave = tid >> 6, lane = tid & 63;
  const unsigned short* Kg = kvb + (size_t)bt * (NN * DD);
  const unsigned short* Vg = kvb + (size_t)TT * BB * NN * DD + (size_t)bt * (NN * DD);

  // stage (+bias for K/V), zero pad row 15
  for (int u = tid; u < 16 * 192; u += 256) {
    int r = u / 192, q = (u % 192) * 4;
    if (r < NN) {
      ushort4 kv = *(const ushort4*)(Kg + r * DD + q);
      float4 bb = *(const float4*)(bk + r * DD + q);
      ushort4 o;
      o.x = f2bf(bf2f(kv.x) + bb.x); o.y = f2bf(bf2f(kv.y) + bb.y);
      o.z = f2bf(bf2f(kv.z) + bb.z); o.w = f2bf(bf2f(kv.w) + bb.w);
      *(ushort4*)&Kl[r * 776 + q] = o;
      ushort4 vv = *(const ushort4*)(Vg + r * DD + q);
      float4 vb4 = *(const float4*)(bv + r * DD + q);
      ushort4 o2;
      o2.x = f2bf(bf2f(vv.x) + vb4.x); o2.y = f2bf(bf2f(vv.y) + vb4.y);
      o2.z = f2bf(bf2f(vv.z) + vb4.z); o2.w = f2bf(bf2f(vv.w) + vb4.w);
      *(ushort4*)&Vl[r * 776 + q] = o2;
    } else {
      ushort4 z; z.x = z.y = z.z = z.w = 0;
      *(ushort4*)&Kl[r * 776 + q] = z;
      *(ushort4*)&Vl[r * 776 + q] = z;
    }
  }
  __syncthreads();

  // per-row LN + softplus (rows 0..14: K with 1/sqrt(D) scale; 15..29: V)
  for (int row = wave; row < 30; row += 4) {
    unsigned short* P = (row < NN) ? (Kl + row * 776) : (Vl + (row - NN) * 776);
    const float* g = (row < NN) ? kg : vg;
    const float* be = (row < NN) ? kbe : vbe;
    float s = 0.f, sq = 0.f;
    float xv[12];
    #pragma unroll
    for (int j = 0; j < 12; j++) {
      float v = bf2f(P[lane + j * 64]);
      xv[j] = v; s += v; sq += v * v;
    }
    #pragma unroll
    for (int off = 32; off; off >>= 1) {
      s += __shfl_down(s, off);
      sq += __shfl_down(sq, off);
    }
    s = __shfl(s, 0); sq = __shfl(sq, 0);
    float mean = s * (1.f / 768.f);
    float rstd = rsqrtf(fmaxf(sq * (1.f / 768.f) - mean * mean, 0.f) + 1e-5f);
    float scale = (row < NN) ? 0.03608439182435161f : 1.f;  // 1/sqrt(768)
    #pragma unroll
    for (int j = 0; j < 12; j++) {
      int d = lane + j * 64;
      float y = (xv[j] - mean) * rstd * g[d] + be[d];
      float sp = fmaxf(y, 0.f) + log1pf(expf(-fabsf(y)));
      P[d] = f2bf(sp * scale);
    }
  }
  __syncthreads();

  // S = K V^T via MFMA; wave w handles k quarter
  int hi = lane >> 4, lo = lane & 15;
  f32x4 acc = (f32x4)0.f;
  #pragma unroll
  for (int ks = 0; ks < 6; ks++) {
    int k = wave * 192 + ks * 32 + hi * 8;
    bf16x8 a = *(const bf16x8*)(Kl + lo * 776 + k);
    bf16x8 v = *(const bf16x8*)(Vl + lo * 776 + k);
    acc = __builtin_amdgcn_mfma_f32_16x16x32_bf16(a, v, acc, 0, 0, 0);
  }
  #pragma unroll
  for (int q = 0; q < 4; q++) Sl[wave][hi * 4 + q][lo] = acc[q];
  __syncthreads();
  if (tid < NN * NN) {
    int n = tid / NN, m = tid % NN;
    Ss[n][m] = Sl[0][n][m] + Sl[1][n][m] + Sl[2][n][m] + Sl[3][n][m];
  }
  __syncthreads();
  if (tid < NN * NN) {
    int n = tid / NN, m = tid % NN;
    float s = 0.f, sq = 0.f;
    #pragma unroll
    for (int mm = 0; mm < NN; mm++) {
      float v = Ss[n][mm];
      s += v; sq += v * v;
    }
    float mean = s * (1.f / 15.f);
    float rstd = rsqrtf(fmaxf(sq * (1.f / 15.f) - mean * mean, 0.f) + 1e-5f);
    float y = (Ss[n][m] - mean) * rstd * ng[m] + nbe[m];
    float now = fmaxf(y, 0.f);
    float c = Cw[(b * TT + t) * NN + n];
    atomicAdd(out + (b * NN + n) * NN + m, c * now);
  }
}

extern "C" void kernel_launch(void* const* d_in, const int* in_sizes, int n_in,
                              void* d_out, int out_size, void* d_ws, size_t ws_size,
                              hipStream_t stream) {
  const float* x         = (const float*)d_in[0];
  const float* labels    = (const float*)d_in[1];
  const float* cell_past = (const float*)d_in[2];
  const float* Wk        = (const float*)d_in[3];
  const float* Wv        = (const float*)d_in[4];
  const float* bk        = (const float*)d_in[5];
  const float* bv        = (const float*)d_in[6];
  const float* w_in      = (const float*)d_in[7];
  const float* b_in      = (const float*)d_in[8];
  const float* kg        = (const float*)d_in[9];
  const float* kbe       = (const float*)d_in[10];
  const float* vg        = (const float*)d_in[11];
  const float* vbe       = (const float*)d_in[12];
  const float* ng        = (const float*)d_in[13];
  const float* nbe       = (const float*)d_in[14];
  float* out = (float*)d_out;
  char* ws = (char*)d_ws;

  unsigned short* Wt  = (unsigned short*)ws;                    // 70,778,880 B
  unsigned short* xb  = (unsigned short*)(ws + 70778880);       // 94,371,840 B
  unsigned short* kvb = (unsigned short*)(ws + 165150720);      // 94,371,840 B
  float* nrm   = (float*)(ws + 259522560);                      // 114,688 B
  float* Iw    = (float*)(ws + 259637248);                      // 122,880 B
  float* Cw    = (float*)(ws + 259760128);                      // 122,880 B
  float* Callw = (float*)(ws + 259883008);                      // 3,840 B
  unsigned* mmx = (unsigned*)(ws + 259886848);                  // 8 B

  k_init<<<1, 64, 0, stream>>>(mmx);
  k_nrm<<<109, 256, 0, stream>>>(labels, nrm, mmx);
  k_cvtw<<<8640, 256, 0, stream>>>(Wk, Wv, Wt);
  k_cvtx<<<7680, 256, 0, stream>>>(x, w_in, b_in, nrm, mmx, xb, Iw);
  k_suffix<<<4, 256, 0, stream>>>(Iw, Cw, Callw);
  k_outinit<<<57, 256, 0, stream>>>(cell_past, Callw, out);
  k_gemm<<<2880, 256, 0, stream>>>(xb, Wt, kvb);
  k_scan<<<2048, 256, 0, stream>>>(kvb, bk, bv, kg, kbe, vg, vbe, ng, nbe, Cw, out);
}